// Round 1
// baseline (258.358 us; speedup 1.0000x reference)
//
#include <hip/hip_runtime.h>

// Problem shapes (fixed by setup_inputs)
constexpr int NB = 32;       // batch
constexpr int NL = 8400;     // anchors
constexpr int NC = 1;        // classes
constexpr int NG = 50;       // max gts
constexpr int NKP = 17;      // keypoints
constexpr int TOPK = 13;
constexpr int BLTOT = NB * NL;
constexpr float FEPS = 1e-9f;

// ---------------- Kernel A: per-(b,gt) top-13 -> claim bitmask ----------------
// One block per (b,i) row. Metric m[j] = score^1 * iou^6 * in_gts into LDS,
// then 13 rounds of block argmax with JAX top_k tie-break (value desc, idx asc).
__global__ __launch_bounds__(256) void topk_claim_kernel(
    const float* __restrict__ pred_scores, const float* __restrict__ pred_bboxes,
    const float* __restrict__ anchor_points, const int* __restrict__ gt_labels,
    const float* __restrict__ gt_bboxes, const float* __restrict__ pad_gt_mask,
    unsigned long long* __restrict__ claims)
{
    __shared__ float m[NL];
    __shared__ float sv[256];
    __shared__ int   si[256];
    const int row = blockIdx.x;          // b*NG + i
    const int b = row / NG, i = row % NG;
    if (pad_gt_mask[row] <= 0.f) return;   // masked gt: contributes nothing (uniform exit)

    const float4 g = reinterpret_cast<const float4*>(gt_bboxes)[row];
    const int lab = gt_labels[row];
    const float garea = (g.z - g.x) * (g.w - g.y);

    for (int j = threadIdx.x; j < NL; j += 256) {
        const float4 p = reinterpret_cast<const float4*>(pred_bboxes)[b * NL + j];
        const float ix1 = fmaxf(g.x, p.x), iy1 = fmaxf(g.y, p.y);
        const float ix2 = fminf(g.z, p.z), iy2 = fminf(g.w, p.w);
        const float iw = fmaxf(ix2 - ix1, 0.f), ih = fmaxf(iy2 - iy1, 0.f);
        const float inter = iw * ih;
        const float parea = (p.z - p.x) * (p.w - p.y);
        const float iou = inter / (garea + parea - inter + FEPS);
        const float2 a = reinterpret_cast<const float2*>(anchor_points)[j];
        const float din = fminf(fminf(a.x - g.x, a.y - g.y), fminf(g.z - a.x, g.w - a.y));
        const float s = pred_scores[(b * NL + j) * NC + lab];
        const float i2 = iou * iou;
        m[j] = (din > FEPS) ? s * i2 * i2 * i2 : 0.f;   // align * is_in_gts
    }
    __syncthreads();

    for (int t = 0; t < TOPK; ++t) {
        float bv = -1.f; int bi = NL;
        for (int j = threadIdx.x; j < NL; j += 256) {
            const float v = m[j];
            if (v > bv) { bv = v; bi = j; }  // first max within strided subset => lowest j
        }
        sv[threadIdx.x] = bv; si[threadIdx.x] = bi;
        __syncthreads();
        for (int srd = 128; srd > 0; srd >>= 1) {
            if (threadIdx.x < srd) {
                const float v2 = sv[threadIdx.x + srd];
                const int   j2 = si[threadIdx.x + srd];
                if (v2 > sv[threadIdx.x] || (v2 == sv[threadIdx.x] && j2 < si[threadIdx.x])) {
                    sv[threadIdx.x] = v2; si[threadIdx.x] = j2;
                }
            }
            __syncthreads();
        }
        if (threadIdx.x == 0) {
            const int j = si[0];
            // mask_pos multiplies by is_in_gts: only claim if anchor strictly inside gt
            const float2 a = reinterpret_cast<const float2*>(anchor_points)[j];
            const float din = fminf(fminf(a.x - g.x, a.y - g.y), fminf(g.z - a.x, g.w - a.y));
            if (din > FEPS)
                atomicOr(&claims[b * NL + j], 1ull << i);
            m[j] = -1.f;   // exclude from later rounds
        }
        __syncthreads();
    }
}

// ---------------- Kernel B: per-anchor resolve -> agi, align_val, row maxima ----------------
__global__ __launch_bounds__(256) void resolve_kernel(
    const float* __restrict__ pred_scores, const float* __restrict__ pred_bboxes,
    const int* __restrict__ gt_labels, const float* __restrict__ gt_bboxes,
    const unsigned long long* __restrict__ claims,
    int* __restrict__ agi_arr, float* __restrict__ align_arr,
    unsigned* __restrict__ rma, unsigned* __restrict__ rmi)
{
    const int idx = blockIdx.x * 256 + threadIdx.x;   // b*NL + j
    if (idx >= BLTOT) return;
    const int b = idx / NL;
    const unsigned long long M = claims[idx];
    const int mps = __popcll(M);
    int agi = -1;
    float av = 0.f;
    if (mps >= 1) {
        const float4 p = reinterpret_cast<const float4*>(pred_bboxes)[idx];
        const float parea = (p.z - p.x) * (p.w - p.y);
        if (mps == 1) {
            agi = __builtin_ctzll(M);
        } else {
            // reference: column replaced by is_max_iou over ALL gts (incl. padded),
            // jnp.argmax first-occurrence tie-break -> strict '>'
            float best = -1.f;
            for (int i = 0; i < NG; ++i) {
                const float4 g = reinterpret_cast<const float4*>(gt_bboxes)[b * NG + i];
                const float ix1 = fmaxf(g.x, p.x), iy1 = fmaxf(g.y, p.y);
                const float ix2 = fminf(g.z, p.z), iy2 = fminf(g.w, p.w);
                const float iw = fmaxf(ix2 - ix1, 0.f), ih = fmaxf(iy2 - iy1, 0.f);
                const float inter = iw * ih;
                const float ga = (g.z - g.x) * (g.w - g.y);
                const float iou = inter / (ga + parea - inter + FEPS);
                if (iou > best) { best = iou; agi = i; }
            }
        }
        // align (NOT masked by in_gts) and iou for the assigned pair
        const float4 g = reinterpret_cast<const float4*>(gt_bboxes)[b * NG + agi];
        const float ix1 = fmaxf(g.x, p.x), iy1 = fmaxf(g.y, p.y);
        const float ix2 = fminf(g.z, p.z), iy2 = fminf(g.w, p.w);
        const float iw = fmaxf(ix2 - ix1, 0.f), ih = fmaxf(iy2 - iy1, 0.f);
        const float inter = iw * ih;
        const float ga = (g.z - g.x) * (g.w - g.y);
        const float iou = inter / (ga + parea - inter + FEPS);
        const int lab = gt_labels[b * NG + agi];
        const float s = pred_scores[idx * NC + lab];
        const float i2 = iou * iou;
        av = s * i2 * i2 * i2;
        // per-row maxima of align*mask and iou*mask (all values >= 0 -> uint order ok)
        atomicMax(&rma[b * NG + agi], __float_as_uint(av));
        atomicMax(&rmi[b * NG + agi], __float_as_uint(iou));
    }
    agi_arr[idx] = agi;
    align_arr[idx] = av;
}

// ---------------- Kernel C: labels / bboxes / scores / agi_flat ----------------
__global__ __launch_bounds__(256) void finalize_kernel(
    const int* __restrict__ gt_labels, const float* __restrict__ gt_bboxes,
    const int* __restrict__ agi_arr, const float* __restrict__ align_arr,
    const unsigned* __restrict__ rma, const unsigned* __restrict__ rmi,
    const int* __restrict__ bg_ptr, float* __restrict__ out)
{
    const int idx = blockIdx.x * 256 + threadIdx.x;
    if (idx >= BLTOT) return;
    const int b = idx / NL;
    const int agi = agi_arr[idx];
    const int ag = (agi < 0) ? 0 : agi;     // reference gathers gt 0 when unassigned
    const int bg = *bg_ptr;
    const int lab = gt_labels[b * NG + ag];

    float* labels = out;
    float* bboxes = out + (size_t)BLTOT;
    float* scores = out + (size_t)56 * BLTOT;
    float* agif   = out + (size_t)57 * BLTOT;

    labels[idx] = (agi >= 0) ? (float)lab : (float)bg;
    reinterpret_cast<float4*>(bboxes)[idx] =
        reinterpret_cast<const float4*>(gt_bboxes)[b * NG + ag];
    agif[idx] = (float)(ag + b * NG);

    float sc = 0.f;
    if (agi >= 0 && lab != bg) {   // one_hot with bg column removed
        const float mm = __uint_as_float(rma[b * NG + agi]);
        const float mi = __uint_as_float(rmi[b * NG + agi]);
        sc = align_arr[idx] / (mm + FEPS) * mi;
    }
    scores[idx] = sc;
}

// ---------------- Kernel D: poses gather (B,L,K,3) ----------------
__global__ __launch_bounds__(256) void poses_kernel(
    const float* __restrict__ gt_poses, const int* __restrict__ agi_arr,
    float* __restrict__ out_poses)
{
    const int idx = blockIdx.x * 256 + threadIdx.x;
    if (idx >= BLTOT * NKP * 3) return;
    const int p = idx / (NKP * 3);
    const int r = idx % (NKP * 3);
    const int b = p / NL;
    int agi = agi_arr[p]; if (agi < 0) agi = 0;
    out_poses[idx] = gt_poses[(b * NG + agi) * (NKP * 3) + r];
}

extern "C" void kernel_launch(void* const* d_in, const int* in_sizes, int n_in,
                              void* d_out, int out_size, void* d_ws, size_t ws_size,
                              hipStream_t stream)
{
    const float* pred_scores   = (const float*)d_in[0];
    const float* pred_bboxes   = (const float*)d_in[1];
    // d_in[2] pred_poses: unused by the reference
    const float* anchor_points = (const float*)d_in[3];
    const int*   gt_labels     = (const int*)d_in[4];
    const float* gt_bboxes     = (const float*)d_in[5];
    const float* gt_poses      = (const float*)d_in[6];
    const float* pad_gt_mask   = (const float*)d_in[7];
    const int*   bg_ptr        = (const int*)d_in[8];

    // workspace layout (~4.3 MB)
    char* w = (char*)d_ws;
    unsigned long long* claims = (unsigned long long*)w;                      // BLTOT*8
    unsigned* rma = (unsigned*)(w + (size_t)BLTOT * 8);                        // NB*NG*4
    unsigned* rmi = (unsigned*)(w + (size_t)BLTOT * 8 + NB * NG * 4);          // NB*NG*4
    int*   agi_arr   = (int*)  (w + (size_t)BLTOT * 8 + 2 * NB * NG * 4);      // BLTOT*4
    float* align_arr = (float*)(w + (size_t)BLTOT * 8 + 2 * NB * NG * 4
                                  + (size_t)BLTOT * 4);                        // BLTOT*4

    hipMemsetAsync(d_ws, 0, (size_t)BLTOT * 8 + 2 * NB * NG * 4, stream);

    topk_claim_kernel<<<NB * NG, 256, 0, stream>>>(
        pred_scores, pred_bboxes, anchor_points, gt_labels, gt_bboxes,
        pad_gt_mask, claims);

    resolve_kernel<<<(BLTOT + 255) / 256, 256, 0, stream>>>(
        pred_scores, pred_bboxes, gt_labels, gt_bboxes, claims,
        agi_arr, align_arr, rma, rmi);

    finalize_kernel<<<(BLTOT + 255) / 256, 256, 0, stream>>>(
        gt_labels, gt_bboxes, agi_arr, align_arr, rma, rmi, bg_ptr,
        (float*)d_out);

    poses_kernel<<<(BLTOT * NKP * 3 + 255) / 256, 256, 0, stream>>>(
        gt_poses, agi_arr, (float*)d_out + (size_t)5 * BLTOT);
}

// Round 2
// 201.542 us; speedup vs baseline: 1.2819x; 1.2819x over previous
//
#include <hip/hip_runtime.h>

// Problem shapes (fixed by setup_inputs)
constexpr int NB = 32;       // batch
constexpr int NL = 8400;     // anchors
constexpr int NC = 1;        // classes
constexpr int NG = 50;       // max gts
constexpr int NKP = 17;      // keypoints
constexpr int TOPK = 13;
constexpr int BLTOT = NB * NL;
constexpr float FEPS = 1e-9f;

// ---------------- Kernel A: per-(b,gt) single-pass top-13 -> claim bitmask ----------------
// One block (256 thr) per (b,i) row. Each thread streams its 33 strided anchors once,
// keeping a register-resident sorted top-13 (value desc, index asc — exact JAX top_k
// tie-break since j increases monotonically within a thread, so strict '>' suffices).
// Then an 8-level LDS merge tree of sorted 13-lists (8 barriers total).
__global__ __launch_bounds__(256) void topk_claim_kernel(
    const float* __restrict__ pred_scores, const float* __restrict__ pred_bboxes,
    const float* __restrict__ anchor_points, const int* __restrict__ gt_labels,
    const float* __restrict__ gt_bboxes, const float* __restrict__ pad_gt_mask,
    unsigned long long* __restrict__ claims)
{
    __shared__ float lv[256 * TOPK];   // 13312 B
    __shared__ int   li[256 * TOPK];   // 13312 B
    const int row = blockIdx.x;        // b*NG + i
    const int b = row / NG, i = row % NG;
    if (pad_gt_mask[row] <= 0.f) return;   // masked gt contributes nothing (block-uniform)

    const float4 g = reinterpret_cast<const float4*>(gt_bboxes)[row];
    const int lab = gt_labels[row];
    const float garea = (g.z - g.x) * (g.w - g.y);
    const int tid = threadIdx.x;

    float tv[TOPK]; int tj[TOPK];
    #pragma unroll
    for (int k = 0; k < TOPK; ++k) { tv[k] = -1.f; tj[k] = NL; }

    for (int j = tid; j < NL; j += 256) {
        const float4 p = reinterpret_cast<const float4*>(pred_bboxes)[b * NL + j];
        const float ix1 = fmaxf(g.x, p.x), iy1 = fmaxf(g.y, p.y);
        const float ix2 = fminf(g.z, p.z), iy2 = fminf(g.w, p.w);
        const float iw = fmaxf(ix2 - ix1, 0.f), ih = fmaxf(iy2 - iy1, 0.f);
        const float inter = iw * ih;
        const float parea = (p.z - p.x) * (p.w - p.y);
        const float iou = inter / (garea + parea - inter + FEPS);
        const float2 a = reinterpret_cast<const float2*>(anchor_points)[j];
        const float din = fminf(fminf(a.x - g.x, a.y - g.y), fminf(g.z - a.x, g.w - a.y));
        const float s = pred_scores[(b * NL + j) * NC + lab];
        const float i2 = iou * iou;
        const float mj = (din > FEPS) ? s * i2 * i2 * i2 : 0.f;  // align * is_in_gts

        if (mj > tv[TOPK - 1]) {            // strict: equal value w/ larger j loses
            tv[TOPK - 1] = mj; tj[TOPK - 1] = j;
            #pragma unroll
            for (int k = TOPK - 1; k > 0; --k) {
                if (tv[k] > tv[k - 1]) {    // equal → stable (smaller j stays ahead)
                    const float fv = tv[k]; tv[k] = tv[k - 1]; tv[k - 1] = fv;
                    const int fi = tj[k]; tj[k] = tj[k - 1]; tj[k - 1] = fi;
                }
            }
        }
    }

    #pragma unroll
    for (int k = 0; k < TOPK; ++k) { lv[tid * TOPK + k] = tv[k]; li[tid * TOPK + k] = tj[k]; }
    __syncthreads();

    // merge tree: thread t (t % 2s == 0) merges list[t] and list[t+s] -> list[t]
    for (int stride = 1; stride < 256; stride <<= 1) {
        if ((tid & (2 * stride - 1)) == 0) {
            const int aB = tid * TOPK, bB = (tid + stride) * TOPK;
            float mv[TOPK]; int mi[TOPK];
            int a = 0, c = 0;
            #pragma unroll
            for (int k = 0; k < TOPK; ++k) {
                const float va = lv[aB + a], vb = lv[bB + c];
                const int ia = li[aB + a], ib = li[bB + c];
                const bool ta = (va > vb) || (va == vb && ia < ib);
                mv[k] = ta ? va : vb; mi[k] = ta ? ia : ib;
                if (ta) ++a; else ++c;
            }
            #pragma unroll
            for (int k = 0; k < TOPK; ++k) { lv[aB + k] = mv[k]; li[aB + k] = mi[k]; }
        }
        __syncthreads();
    }

    if (tid == 0) {
        for (int k = 0; k < TOPK; ++k) {
            const int j = li[k];
            // mask_pos multiplies by is_in_gts: only claim if anchor strictly inside gt
            const float2 a = reinterpret_cast<const float2*>(anchor_points)[j];
            const float din = fminf(fminf(a.x - g.x, a.y - g.y), fminf(g.z - a.x, g.w - a.y));
            if (din > FEPS)
                atomicOr(&claims[b * NL + j], 1ull << i);
        }
    }
}

// ---------------- Kernel B: per-anchor resolve -> agi, align_val, row maxima ----------------
__global__ __launch_bounds__(256) void resolve_kernel(
    const float* __restrict__ pred_scores, const float* __restrict__ pred_bboxes,
    const int* __restrict__ gt_labels, const float* __restrict__ gt_bboxes,
    const unsigned long long* __restrict__ claims,
    int* __restrict__ agi_arr, float* __restrict__ align_arr,
    unsigned* __restrict__ rma, unsigned* __restrict__ rmi)
{
    const int idx = blockIdx.x * 256 + threadIdx.x;   // b*NL + j
    if (idx >= BLTOT) return;
    const int b = idx / NL;
    const unsigned long long M = claims[idx];
    const int mps = __popcll(M);
    int agi = -1;
    float av = 0.f;
    if (mps >= 1) {
        const float4 p = reinterpret_cast<const float4*>(pred_bboxes)[idx];
        const float parea = (p.z - p.x) * (p.w - p.y);
        if (mps == 1) {
            agi = __builtin_ctzll(M);
        } else {
            // reference: column replaced by is_max_iou over ALL gts (incl. padded),
            // jnp.argmax first-occurrence tie-break -> strict '>'
            float best = -1.f;
            for (int i = 0; i < NG; ++i) {
                const float4 g = reinterpret_cast<const float4*>(gt_bboxes)[b * NG + i];
                const float ix1 = fmaxf(g.x, p.x), iy1 = fmaxf(g.y, p.y);
                const float ix2 = fminf(g.z, p.z), iy2 = fminf(g.w, p.w);
                const float iw = fmaxf(ix2 - ix1, 0.f), ih = fmaxf(iy2 - iy1, 0.f);
                const float inter = iw * ih;
                const float ga = (g.z - g.x) * (g.w - g.y);
                const float iou = inter / (ga + parea - inter + FEPS);
                if (iou > best) { best = iou; agi = i; }
            }
        }
        // align (NOT masked by in_gts) and iou for the assigned pair
        const float4 g = reinterpret_cast<const float4*>(gt_bboxes)[b * NG + agi];
        const float ix1 = fmaxf(g.x, p.x), iy1 = fmaxf(g.y, p.y);
        const float ix2 = fminf(g.z, p.z), iy2 = fminf(g.w, p.w);
        const float iw = fmaxf(ix2 - ix1, 0.f), ih = fmaxf(iy2 - iy1, 0.f);
        const float inter = iw * ih;
        const float ga = (g.z - g.x) * (g.w - g.y);
        const float iou = inter / (ga + parea - inter + FEPS);
        const int lab = gt_labels[b * NG + agi];
        const float s = pred_scores[idx * NC + lab];
        const float i2 = iou * iou;
        av = s * i2 * i2 * i2;
        // per-row maxima of align*mask and iou*mask (all values >= 0 -> uint order ok)
        atomicMax(&rma[b * NG + agi], __float_as_uint(av));
        atomicMax(&rmi[b * NG + agi], __float_as_uint(iou));
    }
    agi_arr[idx] = agi;
    align_arr[idx] = av;
}

// ---------------- Kernel C: labels / bboxes / scores / agi_flat ----------------
__global__ __launch_bounds__(256) void finalize_kernel(
    const int* __restrict__ gt_labels, const float* __restrict__ gt_bboxes,
    const int* __restrict__ agi_arr, const float* __restrict__ align_arr,
    const unsigned* __restrict__ rma, const unsigned* __restrict__ rmi,
    const int* __restrict__ bg_ptr, float* __restrict__ out)
{
    const int idx = blockIdx.x * 256 + threadIdx.x;
    if (idx >= BLTOT) return;
    const int b = idx / NL;
    const int agi = agi_arr[idx];
    const int ag = (agi < 0) ? 0 : agi;     // reference gathers gt 0 when unassigned
    const int bg = *bg_ptr;
    const int lab = gt_labels[b * NG + ag];

    float* labels = out;
    float* bboxes = out + (size_t)BLTOT;
    float* scores = out + (size_t)56 * BLTOT;
    float* agif   = out + (size_t)57 * BLTOT;

    labels[idx] = (agi >= 0) ? (float)lab : (float)bg;
    reinterpret_cast<float4*>(bboxes)[idx] =
        reinterpret_cast<const float4*>(gt_bboxes)[b * NG + ag];
    agif[idx] = (float)(ag + b * NG);

    float sc = 0.f;
    if (agi >= 0 && lab != bg) {   // one_hot with bg column removed
        const float mm = __uint_as_float(rma[b * NG + agi]);
        const float mi = __uint_as_float(rmi[b * NG + agi]);
        sc = align_arr[idx] / (mm + FEPS) * mi;
    }
    scores[idx] = sc;
}

// ---------------- Kernel D: poses gather (B,L,K,3) ----------------
__global__ __launch_bounds__(256) void poses_kernel(
    const float* __restrict__ gt_poses, const int* __restrict__ agi_arr,
    float* __restrict__ out_poses)
{
    const int idx = blockIdx.x * 256 + threadIdx.x;
    if (idx >= BLTOT * NKP * 3) return;
    const int p = idx / (NKP * 3);
    const int r = idx % (NKP * 3);
    const int b = p / NL;
    int agi = agi_arr[p]; if (agi < 0) agi = 0;
    out_poses[idx] = gt_poses[(b * NG + agi) * (NKP * 3) + r];
}

extern "C" void kernel_launch(void* const* d_in, const int* in_sizes, int n_in,
                              void* d_out, int out_size, void* d_ws, size_t ws_size,
                              hipStream_t stream)
{
    const float* pred_scores   = (const float*)d_in[0];
    const float* pred_bboxes   = (const float*)d_in[1];
    // d_in[2] pred_poses: unused by the reference
    const float* anchor_points = (const float*)d_in[3];
    const int*   gt_labels     = (const int*)d_in[4];
    const float* gt_bboxes     = (const float*)d_in[5];
    const float* gt_poses      = (const float*)d_in[6];
    const float* pad_gt_mask   = (const float*)d_in[7];
    const int*   bg_ptr        = (const int*)d_in[8];

    // workspace layout (~4.3 MB)
    char* w = (char*)d_ws;
    unsigned long long* claims = (unsigned long long*)w;                      // BLTOT*8
    unsigned* rma = (unsigned*)(w + (size_t)BLTOT * 8);                        // NB*NG*4
    unsigned* rmi = (unsigned*)(w + (size_t)BLTOT * 8 + NB * NG * 4);          // NB*NG*4
    int*   agi_arr   = (int*)  (w + (size_t)BLTOT * 8 + 2 * NB * NG * 4);      // BLTOT*4
    float* align_arr = (float*)(w + (size_t)BLTOT * 8 + 2 * NB * NG * 4
                                  + (size_t)BLTOT * 4);                        // BLTOT*4

    hipMemsetAsync(d_ws, 0, (size_t)BLTOT * 8 + 2 * NB * NG * 4, stream);

    topk_claim_kernel<<<NB * NG, 256, 0, stream>>>(
        pred_scores, pred_bboxes, anchor_points, gt_labels, gt_bboxes,
        pad_gt_mask, claims);

    resolve_kernel<<<(BLTOT + 255) / 256, 256, 0, stream>>>(
        pred_scores, pred_bboxes, gt_labels, gt_bboxes, claims,
        agi_arr, align_arr, rma, rmi);

    finalize_kernel<<<(BLTOT + 255) / 256, 256, 0, stream>>>(
        gt_labels, gt_bboxes, agi_arr, align_arr, rma, rmi, bg_ptr,
        (float*)d_out);

    poses_kernel<<<(BLTOT * NKP * 3 + 255) / 256, 256, 0, stream>>>(
        gt_poses, agi_arr, (float*)d_out + (size_t)5 * BLTOT);
}

// Round 3
// 182.332 us; speedup vs baseline: 1.4170x; 1.1054x over previous
//
#include <hip/hip_runtime.h>

// Problem shapes (fixed by setup_inputs)
constexpr int NB = 32;       // batch
constexpr int NL = 8400;     // anchors
constexpr int NC = 1;        // classes
constexpr int NG = 50;       // max gts
constexpr int NKP = 17;      // keypoints
constexpr int TOPK = 13;
constexpr int BLTOT = NB * NL;
constexpr int NROW = NB * NG;        // 1600
constexpr int CAP = 1024;            // candidate capacity per row (16 slots/lane)
constexpr int JBLK = (NL + 255) / 256;  // 33 anchor-blocks per batch
constexpr float FEPS = 1e-9f;

__device__ __forceinline__ float iou_gp(const float4 g, const float4 p, float garea) {
    const float ix1 = fmaxf(g.x, p.x), iy1 = fmaxf(g.y, p.y);
    const float ix2 = fminf(g.z, p.z), iy2 = fminf(g.w, p.w);
    const float iw = fmaxf(ix2 - ix1, 0.f), ih = fmaxf(iy2 - iy1, 0.f);
    const float inter = iw * ih;
    const float parea = (p.z - p.x) * (p.w - p.y);
    return inter / (garea + parea - inter + FEPS);
}

// ---------------- Kernel A1: per-anchor in-gts bitmask + candidate lists ----------------
__global__ __launch_bounds__(256) void ingts_kernel(
    const float* __restrict__ anchor_points, const float* __restrict__ gt_bboxes,
    const float* __restrict__ pad_gt_mask,
    unsigned long long* __restrict__ ingts, int* __restrict__ cand_cnt,
    int* __restrict__ cand)
{
    __shared__ float4 gbox[NG];
    __shared__ int gact[NG];
    const int b = blockIdx.x / JBLK;
    const int jb = (blockIdx.x % JBLK) * 256;
    if (threadIdx.x < NG) {
        gbox[threadIdx.x] = reinterpret_cast<const float4*>(gt_bboxes)[b * NG + threadIdx.x];
        gact[threadIdx.x] = pad_gt_mask[b * NG + threadIdx.x] > 0.f;
    }
    __syncthreads();
    const int j = jb + threadIdx.x;
    if (j >= NL) return;
    const float2 a = reinterpret_cast<const float2*>(anchor_points)[j];
    unsigned long long m = 0;
    for (int i = 0; i < NG; ++i) {
        const float4 g = gbox[i];
        const float din = fminf(fminf(a.x - g.x, a.y - g.y), fminf(g.z - a.x, g.w - a.y));
        if (din > FEPS) {
            m |= (1ull << i);
            if (gact[i]) {
                const int row = b * NG + i;
                const int slot = atomicAdd(&cand_cnt[row], 1);
                if (slot < CAP) cand[row * CAP + slot] = j;
            }
        }
    }
    ingts[b * NL + j] = m;
}

// ---------------- Kernel B1: one wave per (b,gt) row -> top-13 claims ----------------
// Nonzero metrics exist only among candidates (in-gts anchors). Top-13 =
// sorted nonzero candidates (value desc, idx asc) then smallest-index
// zero-metric anchors. Claims require in-gts (mask_pos *= is_in_gts).
__global__ __launch_bounds__(256) void topk_claim_kernel(
    const float* __restrict__ pred_scores, const float* __restrict__ pred_bboxes,
    const int* __restrict__ gt_labels, const float* __restrict__ gt_bboxes,
    const float* __restrict__ pad_gt_mask,
    const unsigned long long* __restrict__ ingts, const int* __restrict__ cand_cnt,
    const int* __restrict__ cand, unsigned long long* __restrict__ claims)
{
    const int row = blockIdx.x * 4 + (threadIdx.x >> 6);
    const int lane = threadIdx.x & 63;
    if (row >= NROW) return;                 // wave-uniform
    if (pad_gt_mask[row] <= 0.f) return;     // wave-uniform
    const int b = row / NG, i = row % NG;
    const float4 g = reinterpret_cast<const float4*>(gt_bboxes)[row];
    const float garea = (g.z - g.x) * (g.w - g.y);
    const int lab = gt_labels[row];
    const int cnt = min(cand_cnt[row], CAP);

    float v[16]; int jj[16];
    #pragma unroll
    for (int s = 0; s < 16; ++s) {
        float mv = -1.f; int mj = NL + lane;     // sentinel (>= NL, never claimed)
        const int c = s * 64 + lane;
        if (c < cnt) {
            const int j = cand[row * CAP + c];
            const float4 p = reinterpret_cast<const float4*>(pred_bboxes)[b * NL + j];
            const float iou = iou_gp(g, p, garea);
            const float sc = pred_scores[(b * NL + j) * NC + lab];
            const float i2 = iou * iou;
            mv = sc * i2 * i2 * i2;
            mj = j;
        }
        v[s] = mv; jj[s] = mj;
    }

    int ct = 0;
    for (int t = 0; t < TOPK; ++t) {
        float bv = -1.f; int bj = 0x7fffffff;
        #pragma unroll
        for (int s = 0; s < 16; ++s)
            if (v[s] > bv || (v[s] == bv && jj[s] < bj)) { bv = v[s]; bj = jj[s]; }
        for (int off = 32; off; off >>= 1) {
            const float v2 = __shfl_xor(bv, off);
            const int   j2 = __shfl_xor(bj, off);
            if (v2 > bv || (v2 == bv && j2 < bj)) { bv = v2; bj = j2; }
        }
        if (bv <= 0.f) break;                    // remaining slots are zero-fill
        if (lane == 0) atomicOr(&claims[b * NL + bj], 1ull << i);
        ++ct;
        #pragma unroll
        for (int s = 0; s < 16; ++s) if (jj[s] == bj) v[s] = -1.f;
    }

    const int needed = TOPK - ct;   // zero-fill slots: smallest-index zero-metric anchors
    if (needed > 0) {
        int zcum = 0;
        for (int base = 0; base < NL && zcum < needed; base += 64) {
            const int j = base + lane;
            bool zero = false, ing = false;
            if (j < NL) {
                ing = (ingts[b * NL + j] >> i) & 1ull;
                if (!ing) {
                    zero = true;
                } else {
                    const float4 p = reinterpret_cast<const float4*>(pred_bboxes)[b * NL + j];
                    const float iou = iou_gp(g, p, garea);
                    const float sc = pred_scores[(b * NL + j) * NC + lab];
                    const float i2 = iou * iou;
                    zero = (sc * i2 * i2 * i2 == 0.f);
                }
            }
            const unsigned long long bal = __ballot(zero);
            const int rank = zcum + __popcll(bal & ((1ull << lane) - 1ull));
            if (zero && ing && rank < needed)
                atomicOr(&claims[b * NL + j], 1ull << i);
            zcum += __popcll(bal);
        }
    }
}

// ---------------- Kernel B: per-anchor resolve -> agi, align_val, row maxima ----------------
__global__ __launch_bounds__(256) void resolve_kernel(
    const float* __restrict__ pred_scores, const float* __restrict__ pred_bboxes,
    const int* __restrict__ gt_labels, const float* __restrict__ gt_bboxes,
    const unsigned long long* __restrict__ claims,
    int* __restrict__ agi_arr, float* __restrict__ align_arr,
    unsigned* __restrict__ rma, unsigned* __restrict__ rmi)
{
    const int idx = blockIdx.x * 256 + threadIdx.x;   // b*NL + j
    if (idx >= BLTOT) return;
    const int b = idx / NL;
    const unsigned long long M = claims[idx];
    const int mps = __popcll(M);
    int agi = -1;
    float av = 0.f;
    if (mps >= 1) {
        const float4 p = reinterpret_cast<const float4*>(pred_bboxes)[idx];
        if (mps == 1) {
            agi = __builtin_ctzll(M);
        } else {
            // reference: column replaced by is_max_iou over ALL gts (incl. padded),
            // jnp.argmax first-occurrence tie-break -> strict '>'
            float best = -1.f;
            for (int i = 0; i < NG; ++i) {
                const float4 g = reinterpret_cast<const float4*>(gt_bboxes)[b * NG + i];
                const float ga = (g.z - g.x) * (g.w - g.y);
                const float iou = iou_gp(g, p, ga);
                if (iou > best) { best = iou; agi = i; }
            }
        }
        const float4 g = reinterpret_cast<const float4*>(gt_bboxes)[b * NG + agi];
        const float ga = (g.z - g.x) * (g.w - g.y);
        const float iou = iou_gp(g, p, ga);
        const int lab = gt_labels[b * NG + agi];
        const float s = pred_scores[idx * NC + lab];
        const float i2 = iou * iou;
        av = s * i2 * i2 * i2;
        atomicMax(&rma[b * NG + agi], __float_as_uint(av));
        atomicMax(&rmi[b * NG + agi], __float_as_uint(iou));
    }
    agi_arr[idx] = agi;
    align_arr[idx] = av;
}

// ---------------- Kernel C: labels / bboxes / scores / agi_flat ----------------
__global__ __launch_bounds__(256) void finalize_kernel(
    const int* __restrict__ gt_labels, const float* __restrict__ gt_bboxes,
    const int* __restrict__ agi_arr, const float* __restrict__ align_arr,
    const unsigned* __restrict__ rma, const unsigned* __restrict__ rmi,
    const int* __restrict__ bg_ptr, float* __restrict__ out)
{
    const int idx = blockIdx.x * 256 + threadIdx.x;
    if (idx >= BLTOT) return;
    const int b = idx / NL;
    const int agi = agi_arr[idx];
    const int ag = (agi < 0) ? 0 : agi;     // reference gathers gt 0 when unassigned
    const int bg = *bg_ptr;
    const int lab = gt_labels[b * NG + ag];

    float* labels = out;
    float* bboxes = out + (size_t)BLTOT;
    float* scores = out + (size_t)56 * BLTOT;
    float* agif   = out + (size_t)57 * BLTOT;

    labels[idx] = (agi >= 0) ? (float)lab : (float)bg;
    reinterpret_cast<float4*>(bboxes)[idx] =
        reinterpret_cast<const float4*>(gt_bboxes)[b * NG + ag];
    agif[idx] = (float)(ag + b * NG);

    float sc = 0.f;
    if (agi >= 0 && lab != bg) {   // one_hot with bg column removed
        const float mm = __uint_as_float(rma[b * NG + agi]);
        const float mi = __uint_as_float(rmi[b * NG + agi]);
        sc = align_arr[idx] / (mm + FEPS) * mi;
    }
    scores[idx] = sc;
}

// ---------------- Kernel D: poses gather (B,L,K,3), float4 stores ----------------
__global__ __launch_bounds__(256) void poses_kernel(
    const float* __restrict__ gt_poses, const int* __restrict__ agi_arr,
    float* __restrict__ out_poses)
{
    const int q = blockIdx.x * 256 + threadIdx.x;       // float4 index
    constexpr int NQ = BLTOT * NKP * 3 / 4;             // 3,427,200 (divisible)
    if (q >= NQ) return;
    const int e0 = q * 4;
    float4 o;
    #pragma unroll
    for (int c = 0; c < 4; ++c) {
        const int e = e0 + c;
        const int p = e / (NKP * 3);
        const int r = e - p * (NKP * 3);
        const int b = p / NL;
        int a = agi_arr[p]; if (a < 0) a = 0;
        (&o.x)[c] = gt_poses[(b * NG + a) * (NKP * 3) + r];
    }
    reinterpret_cast<float4*>(out_poses)[q] = o;
}

extern "C" void kernel_launch(void* const* d_in, const int* in_sizes, int n_in,
                              void* d_out, int out_size, void* d_ws, size_t ws_size,
                              hipStream_t stream)
{
    const float* pred_scores   = (const float*)d_in[0];
    const float* pred_bboxes   = (const float*)d_in[1];
    // d_in[2] pred_poses: unused by the reference
    const float* anchor_points = (const float*)d_in[3];
    const int*   gt_labels     = (const int*)d_in[4];
    const float* gt_bboxes     = (const float*)d_in[5];
    const float* gt_poses      = (const float*)d_in[6];
    const float* pad_gt_mask   = (const float*)d_in[7];
    const int*   bg_ptr        = (const int*)d_in[8];

    // workspace layout (~12.5 MB). Zeroed region first: [claims|rma|rmi|cand_cnt]
    char* w = (char*)d_ws;
    size_t off = 0;
    unsigned long long* claims = (unsigned long long*)(w + off); off += (size_t)BLTOT * 8;   // 2,150,400
    unsigned* rma = (unsigned*)(w + off); off += (size_t)NROW * 4 * 4;                        // 25,600
    unsigned* rmi = (unsigned*)(w + off); off += (size_t)NROW * 4 * 4;                        // 25,600
    int* cand_cnt = (int*)(w + off); off += (size_t)NROW * 4;                                 // 6,400
    const size_t zero_bytes = off;
    int*   agi_arr   = (int*)  (w + off); off += (size_t)BLTOT * 4;
    float* align_arr = (float*)(w + off); off += (size_t)BLTOT * 4;
    unsigned long long* ingts = (unsigned long long*)(w + off); off += (size_t)BLTOT * 8;
    int* cand = (int*)(w + off); off += (size_t)NROW * CAP * 4;

    hipMemsetAsync(d_ws, 0, zero_bytes, stream);

    ingts_kernel<<<NB * JBLK, 256, 0, stream>>>(
        anchor_points, gt_bboxes, pad_gt_mask, ingts, cand_cnt, cand);

    topk_claim_kernel<<<(NROW + 3) / 4, 256, 0, stream>>>(
        pred_scores, pred_bboxes, gt_labels, gt_bboxes, pad_gt_mask,
        ingts, cand_cnt, cand, claims);

    resolve_kernel<<<(BLTOT + 255) / 256, 256, 0, stream>>>(
        pred_scores, pred_bboxes, gt_labels, gt_bboxes, claims,
        agi_arr, align_arr, rma, rmi);

    finalize_kernel<<<(BLTOT + 255) / 256, 256, 0, stream>>>(
        gt_labels, gt_bboxes, agi_arr, align_arr, rma, rmi, bg_ptr,
        (float*)d_out);

    poses_kernel<<<(BLTOT * NKP * 3 / 4 + 255) / 256, 256, 0, stream>>>(
        gt_poses, agi_arr, (float*)d_out + (size_t)5 * BLTOT);
}

// Round 5
// 179.590 us; speedup vs baseline: 1.4386x; 1.0153x over previous
//
#include <hip/hip_runtime.h>

// Problem shapes (fixed by setup_inputs)
constexpr int NB = 32;       // batch
constexpr int NL = 8400;     // anchors
constexpr int NC = 1;        // classes
constexpr int NG = 50;       // max gts
constexpr int NKP = 17;      // keypoints
constexpr int TOPK = 13;
constexpr int BLTOT = NB * NL;
constexpr int NROW = NB * NG;        // 1600
constexpr int CAP = 1024;            // candidate capacity per row (16 slots/lane)
constexpr int JBLK = (NL + 255) / 256;  // 33 anchor-blocks per batch
constexpr float FEPS = 1e-9f;

typedef float f32x4 __attribute__((ext_vector_type(4)));  // native vec for nontemporal

__device__ __forceinline__ float iou_gp(const float4 g, const float4 p, float garea) {
    const float ix1 = fmaxf(g.x, p.x), iy1 = fmaxf(g.y, p.y);
    const float ix2 = fminf(g.z, p.z), iy2 = fminf(g.w, p.w);
    const float iw = fmaxf(ix2 - ix1, 0.f), ih = fmaxf(iy2 - iy1, 0.f);
    const float inter = iw * ih;
    const float parea = (p.z - p.x) * (p.w - p.y);
    return inter / (garea + parea - inter + FEPS);
}

// ---------------- Kernel A1: per-anchor in-gts bitmask + candidate lists ----------------
// Also zeroes this anchor's claim word (safe: topk runs in a later dispatch).
__global__ __launch_bounds__(256) void ingts_kernel(
    const float* __restrict__ anchor_points, const float* __restrict__ gt_bboxes,
    const float* __restrict__ pad_gt_mask,
    unsigned long long* __restrict__ ingts, int* __restrict__ cand_cnt,
    int* __restrict__ cand, unsigned long long* __restrict__ claims)
{
    __shared__ float4 gbox[NG];
    __shared__ int gact[NG];
    const int b = blockIdx.x / JBLK;
    const int jb = (blockIdx.x % JBLK) * 256;
    if (threadIdx.x < NG) {
        gbox[threadIdx.x] = reinterpret_cast<const float4*>(gt_bboxes)[b * NG + threadIdx.x];
        gact[threadIdx.x] = pad_gt_mask[b * NG + threadIdx.x] > 0.f;
    }
    __syncthreads();
    const int j = jb + threadIdx.x;
    if (j >= NL) return;
    claims[b * NL + j] = 0ull;
    const float2 a = reinterpret_cast<const float2*>(anchor_points)[j];
    unsigned long long m = 0;
    for (int i = 0; i < NG; ++i) {
        const float4 g = gbox[i];
        const float din = fminf(fminf(a.x - g.x, a.y - g.y), fminf(g.z - a.x, g.w - a.y));
        if (din > FEPS) {
            m |= (1ull << i);
            if (gact[i]) {
                const int row = b * NG + i;
                const int slot = atomicAdd(&cand_cnt[row], 1);
                if (slot < CAP) cand[row * CAP + slot] = j;
            }
        }
    }
    ingts[b * NL + j] = m;
}

// ---------------- Kernel B1: one wave per (b,gt) row -> top-13 claims ----------------
// Nonzero metrics exist only among candidates (in-gts anchors). Top-13 =
// sorted nonzero candidates (value desc, idx asc) then smallest-index
// zero-metric anchors. Claims require in-gts (mask_pos *= is_in_gts).
__global__ __launch_bounds__(256) void topk_claim_kernel(
    const float* __restrict__ pred_scores, const float* __restrict__ pred_bboxes,
    const int* __restrict__ gt_labels, const float* __restrict__ gt_bboxes,
    const float* __restrict__ pad_gt_mask,
    const unsigned long long* __restrict__ ingts, const int* __restrict__ cand_cnt,
    const int* __restrict__ cand, unsigned long long* __restrict__ claims)
{
    const int row = blockIdx.x * 4 + (threadIdx.x >> 6);
    const int lane = threadIdx.x & 63;
    if (row >= NROW) return;                 // wave-uniform
    if (pad_gt_mask[row] <= 0.f) return;     // wave-uniform
    const int b = row / NG, i = row % NG;
    const float4 g = reinterpret_cast<const float4*>(gt_bboxes)[row];
    const float garea = (g.z - g.x) * (g.w - g.y);
    const int lab = gt_labels[row];
    const int cnt = min(cand_cnt[row], CAP);

    float v[16]; int jj[16];
    #pragma unroll
    for (int s = 0; s < 16; ++s) {
        float mv = -1.f; int mj = NL + lane;     // sentinel (>= NL, never claimed)
        const int c = s * 64 + lane;
        if (c < cnt) {
            const int j = cand[row * CAP + c];
            const float4 p = reinterpret_cast<const float4*>(pred_bboxes)[b * NL + j];
            const float iou = iou_gp(g, p, garea);
            const float sc = pred_scores[(b * NL + j) * NC + lab];
            const float i2 = iou * iou;
            mv = sc * i2 * i2 * i2;
            mj = j;
        }
        v[s] = mv; jj[s] = mj;
    }

    int ct = 0;
    for (int t = 0; t < TOPK; ++t) {
        float bv = -1.f; int bj = 0x7fffffff;
        #pragma unroll
        for (int s = 0; s < 16; ++s)
            if (v[s] > bv || (v[s] == bv && jj[s] < bj)) { bv = v[s]; bj = jj[s]; }
        for (int off = 32; off; off >>= 1) {
            const float v2 = __shfl_xor(bv, off);
            const int   j2 = __shfl_xor(bj, off);
            if (v2 > bv || (v2 == bv && j2 < bj)) { bv = v2; bj = j2; }
        }
        if (bv <= 0.f) break;                    // remaining slots are zero-fill
        if (lane == 0) atomicOr(&claims[b * NL + bj], 1ull << i);
        ++ct;
        #pragma unroll
        for (int s = 0; s < 16; ++s) if (jj[s] == bj) v[s] = -1.f;
    }

    const int needed = TOPK - ct;   // zero-fill slots: smallest-index zero-metric anchors
    if (needed > 0) {
        int zcum = 0;
        for (int base = 0; base < NL && zcum < needed; base += 64) {
            const int j = base + lane;
            bool zero = false, ing = false;
            if (j < NL) {
                ing = (ingts[b * NL + j] >> i) & 1ull;
                if (!ing) {
                    zero = true;
                } else {
                    const float4 p = reinterpret_cast<const float4*>(pred_bboxes)[b * NL + j];
                    const float iou = iou_gp(g, p, garea);
                    const float sc = pred_scores[(b * NL + j) * NC + lab];
                    const float i2 = iou * iou;
                    zero = (sc * i2 * i2 * i2 == 0.f);
                }
            }
            const unsigned long long bal = __ballot(zero);
            const int rank = zcum + __popcll(bal & ((1ull << lane) - 1ull));
            if (zero && ing && rank < needed)
                atomicOr(&claims[b * NL + j], 1ull << i);
            zcum += __popcll(bal);
        }
    }
}

// ---------------- Kernel B: per-anchor resolve -> agi, align_val, row maxima ----------------
__global__ __launch_bounds__(256) void resolve_kernel(
    const float* __restrict__ pred_scores, const float* __restrict__ pred_bboxes,
    const int* __restrict__ gt_labels, const float* __restrict__ gt_bboxes,
    const unsigned long long* __restrict__ claims,
    int* __restrict__ agi_arr, float* __restrict__ align_arr,
    unsigned* __restrict__ rma, unsigned* __restrict__ rmi)
{
    const int idx = blockIdx.x * 256 + threadIdx.x;   // b*NL + j
    if (idx >= BLTOT) return;
    const int b = idx / NL;
    const unsigned long long M = claims[idx];
    const int mps = __popcll(M);
    int agi = -1;
    float av = 0.f;
    if (mps >= 1) {
        const float4 p = reinterpret_cast<const float4*>(pred_bboxes)[idx];
        if (mps == 1) {
            agi = __builtin_ctzll(M);
        } else {
            // reference: column replaced by is_max_iou over ALL gts (incl. padded),
            // jnp.argmax first-occurrence tie-break -> strict '>'
            float best = -1.f;
            for (int i = 0; i < NG; ++i) {
                const float4 g = reinterpret_cast<const float4*>(gt_bboxes)[b * NG + i];
                const float ga = (g.z - g.x) * (g.w - g.y);
                const float iou = iou_gp(g, p, ga);
                if (iou > best) { best = iou; agi = i; }
            }
        }
        const float4 g = reinterpret_cast<const float4*>(gt_bboxes)[b * NG + agi];
        const float ga = (g.z - g.x) * (g.w - g.y);
        const float iou = iou_gp(g, p, ga);
        const int lab = gt_labels[b * NG + agi];
        const float s = pred_scores[idx * NC + lab];
        const float i2 = iou * iou;
        av = s * i2 * i2 * i2;
        atomicMax(&rma[b * NG + agi], __float_as_uint(av));
        atomicMax(&rmi[b * NG + agi], __float_as_uint(iou));
    }
    agi_arr[idx] = agi;
    align_arr[idx] = av;
}

// ---------------- Kernel C: fused labels / bboxes / scores / agi_flat / poses ----------------
__global__ __launch_bounds__(256) void final_kernel(
    const int* __restrict__ gt_labels, const float* __restrict__ gt_bboxes,
    const float* __restrict__ gt_poses,
    const int* __restrict__ agi_arr, const float* __restrict__ align_arr,
    const unsigned* __restrict__ rma, const unsigned* __restrict__ rmi,
    const int* __restrict__ bg_ptr, float* __restrict__ out)
{
    const int idx = blockIdx.x * 256 + threadIdx.x;   // exactly BLTOT threads
    const int b = idx / NL;
    const int agi = agi_arr[idx];
    const int ag = (agi < 0) ? 0 : agi;     // reference gathers gt 0 when unassigned
    const int bg = *bg_ptr;
    const int lab = gt_labels[b * NG + ag];

    float* labels = out;
    float* bboxes = out + (size_t)BLTOT;
    float* poses  = out + (size_t)5 * BLTOT;
    float* scores = out + (size_t)56 * BLTOT;
    float* agif   = out + (size_t)57 * BLTOT;

    labels[idx] = (agi >= 0) ? (float)lab : (float)bg;
    reinterpret_cast<float4*>(bboxes)[idx] =
        reinterpret_cast<const float4*>(gt_bboxes)[b * NG + ag];
    agif[idx] = (float)(ag + b * NG);

    float sc = 0.f;
    if (agi >= 0 && lab != bg) {   // one_hot with bg column removed
        const float mm = __uint_as_float(rma[b * NG + agi]);
        const float mi = __uint_as_float(rmi[b * NG + agi]);
        sc = align_arr[idx] / (mm + FEPS) * mi;
    }
    scores[idx] = sc;

    // poses gather: grid-stride over float4s, coalesced; agi_arr is L2-hot
    constexpr int NQ = BLTOT * NKP * 3 / 4;             // 3,427,200
    for (int q = idx; q < NQ; q += BLTOT) {
        const int e0 = q * 4;
        f32x4 o;
        #pragma unroll
        for (int c = 0; c < 4; ++c) {
            const int e = e0 + c;
            const int p = e / (NKP * 3);
            const int r = e - p * (NKP * 3);
            const int pb = p / NL;
            int a = agi_arr[p]; if (a < 0) a = 0;
            o[c] = gt_poses[(pb * NG + a) * (NKP * 3) + r];
        }
        __builtin_nontemporal_store(o, reinterpret_cast<f32x4*>(poses) + q);
    }
}

extern "C" void kernel_launch(void* const* d_in, const int* in_sizes, int n_in,
                              void* d_out, int out_size, void* d_ws, size_t ws_size,
                              hipStream_t stream)
{
    const float* pred_scores   = (const float*)d_in[0];
    const float* pred_bboxes   = (const float*)d_in[1];
    // d_in[2] pred_poses: unused by the reference
    const float* anchor_points = (const float*)d_in[3];
    const int*   gt_labels     = (const int*)d_in[4];
    const float* gt_bboxes     = (const float*)d_in[5];
    const float* gt_poses      = (const float*)d_in[6];
    const float* pad_gt_mask   = (const float*)d_in[7];
    const int*   bg_ptr        = (const int*)d_in[8];

    // workspace layout. Small zeroed region first: [rma|rmi|cand_cnt]
    char* w = (char*)d_ws;
    size_t off = 0;
    unsigned* rma = (unsigned*)(w + off); off += (size_t)NROW * 4;              // 6,400
    unsigned* rmi = (unsigned*)(w + off); off += (size_t)NROW * 4;              // 6,400
    int* cand_cnt = (int*)(w + off); off += (size_t)NROW * 4;                   // 6,400
    const size_t zero_bytes = off;
    unsigned long long* claims = (unsigned long long*)(w + off); off += (size_t)BLTOT * 8;
    int*   agi_arr   = (int*)  (w + off); off += (size_t)BLTOT * 4;
    float* align_arr = (float*)(w + off); off += (size_t)BLTOT * 4;
    unsigned long long* ingts = (unsigned long long*)(w + off); off += (size_t)BLTOT * 8;
    int* cand = (int*)(w + off); off += (size_t)NROW * CAP * 4;

    (void)hipMemsetAsync(d_ws, 0, zero_bytes, stream);   // 19 KB only; claims zeroed in ingts

    ingts_kernel<<<NB * JBLK, 256, 0, stream>>>(
        anchor_points, gt_bboxes, pad_gt_mask, ingts, cand_cnt, cand, claims);

    topk_claim_kernel<<<(NROW + 3) / 4, 256, 0, stream>>>(
        pred_scores, pred_bboxes, gt_labels, gt_bboxes, pad_gt_mask,
        ingts, cand_cnt, cand, claims);

    resolve_kernel<<<(BLTOT + 255) / 256, 256, 0, stream>>>(
        pred_scores, pred_bboxes, gt_labels, gt_bboxes, claims,
        agi_arr, align_arr, rma, rmi);

    final_kernel<<<BLTOT / 256, 256, 0, stream>>>(
        gt_labels, gt_bboxes, gt_poses, agi_arr, align_arr, rma, rmi, bg_ptr,
        (float*)d_out);
}